// Round 3
// baseline (497.403 us; speedup 1.0000x reference)
//
#include <hip/hip_runtime.h>

typedef unsigned short u16;
typedef unsigned int u32;
typedef __bf16 bf16x8 __attribute__((ext_vector_type(8)));
typedef float f32x4 __attribute__((ext_vector_type(4)));

__device__ __forceinline__ u16 f2bf(float f) {
  union { float f; u32 u; } v; v.f = f;
  u32 r = v.u + 0x7FFFu + ((v.u >> 16) & 1u);
  return (u16)(r >> 16);
}
__device__ __forceinline__ u32 pk2(float a, float b) {
  return (u32)f2bf(a) | ((u32)f2bf(b) << 16);
}

typedef __attribute__((address_space(1))) const void* gvp;
typedef __attribute__((address_space(3))) void* lvp;
__device__ __forceinline__ void gl16(const u16* g, u16* l) {
  __builtin_amdgcn_global_load_lds((gvp)g, (lvp)l, 16, 0, 0);
}

// ---------------- dtype probe: 0 = f32 buffers, 1 = bf16 buffers --------------
__global__ void probe_kernel(const u16* __restrict__ x, int* __restrict__ mode) {
  if (threadIdx.x == 0 && blockIdx.x == 0) {
    int cnt = 0;
    for (int i = 0; i < 512; ++i) {
      int e = (x[i] >> 7) & 0xFF;
      cnt += (e >= 110 && e <= 134) ? 1 : 0;
    }
    *mode = (cnt >= 410) ? 1 : 0;
  }
}

// ---------------- x -> bf16 (contiguous) -------------------------------------
__global__ __launch_bounds__(256) void cast_x(const void* __restrict__ src,
                                              u16* __restrict__ dst, int n,
                                              const int* __restrict__ mode) {
  int i = (blockIdx.x * 256 + threadIdx.x) * 8;
  if (i >= n) return;
  uint4 out;
  if (*mode == 0) {
    const float* s = (const float*)src + i;
    float4 v0 = *(const float4*)s, v1 = *(const float4*)(s + 4);
    out.x = pk2(v0.x, v0.y); out.y = pk2(v0.z, v0.w);
    out.z = pk2(v1.x, v1.y); out.w = pk2(v1.z, v1.w);
  } else {
    out = *(const uint4*)((const u16*)src + i);
  }
  *(uint4*)(dst + i) = out;
}

// ---------------- transpose-cast: dst[n][k] = (bf16)src[k][n] ----------------
__global__ __launch_bounds__(256) void tcast(const void* __restrict__ src,
                                             u16* __restrict__ dst, int srcld,
                                             int dstld, const int* __restrict__ mode) {
  __shared__ __align__(16) u16 T[64 * 72];
  int k0 = blockIdx.x * 64, n0 = blockIdx.y * 64;
  int tid = threadIdx.x;
  bool bf = (*mode != 0);
#pragma unroll
  for (int p = 0; p < 2; ++p) {
    int idx = (tid + p * 256) * 8;
    int r = idx >> 6, c = idx & 63;
    uint4 o;
    if (!bf) {
      const float* s = (const float*)src + (size_t)(k0 + r) * srcld + n0 + c;
      float4 v0 = *(const float4*)s, v1 = *(const float4*)(s + 4);
      o.x = pk2(v0.x, v0.y); o.y = pk2(v0.z, v0.w);
      o.z = pk2(v1.x, v1.y); o.w = pk2(v1.z, v1.w);
    } else {
      o = *(const uint4*)((const u16*)src + (size_t)(k0 + r) * srcld + n0 + c);
    }
    *(uint4*)&T[r * 72 + c] = o;
  }
  __syncthreads();
#pragma unroll
  for (int p = 0; p < 2; ++p) {
    int idx = (tid + p * 256) * 8;
    int n = idx >> 6, kk = idx & 63;
    u16 v[8];
#pragma unroll
    for (int j = 0; j < 8; ++j) v[j] = T[(kk + j) * 72 + n];
    *(uint4*)(dst + (size_t)(n0 + n) * dstld + k0 + kk) = *(uint4*)v;
  }
}

// ---------------- m97-style GEMM: C[M,N] = A[M,K] @ Bt[N,K]^T ----------------
// 128x128 tile, BK=64, 4 waves (2x2), global_load_lds width-16 staging.
// XCD-chunked blockIdx swizzle (bijective: grid % 8 == 0).
template<int OUTM>
__global__ __launch_bounds__(256) void gemm_m97(
    const u16* __restrict__ A, const u16* __restrict__ Bt,
    u16* __restrict__ Qb, u16* __restrict__ Kb, u16* __restrict__ VTg,
    float* __restrict__ Cf, int M, int N, int K, const int* __restrict__ mode) {
  __shared__ __align__(16) u16 As[128 * 64];
  __shared__ __align__(16) u16 Bs[128 * 64];
  int tid = threadIdx.x, wid = tid >> 6, lane = tid & 63;
  int wm = wid >> 1, wn = wid & 1, l15 = lane & 15, lq = lane >> 4;
  int nwg = gridDim.x * gridDim.y;
  int id = blockIdx.y * gridDim.x + blockIdx.x;
  int swz = (id & 7) * (nwg >> 3) + (id >> 3);
  int m0 = (swz % gridDim.x) * 128, n0 = (swz / gridDim.x) * 128;
  int rs = lane >> 3, cs = (lane & 7) * 8;

  f32x4 acc[4][4] = {};

  for (int k0 = 0; k0 < K; k0 += 64) {
    __syncthreads();
#pragma unroll
    for (int p = 0; p < 4; ++p) {
      int r = wid * 32 + p * 8;
      gl16(A  + (size_t)(m0 + r + rs) * K + k0 + cs, &As[r * 64]);
      gl16(Bt + (size_t)(n0 + r + rs) * K + k0 + cs, &Bs[r * 64]);
    }
    __syncthreads();
#pragma unroll
    for (int kk = 0; kk < 64; kk += 32) {
      bf16x8 af[4], bfr[4];
#pragma unroll
      for (int x = 0; x < 4; ++x)
        af[x] = *(const bf16x8*)&As[(wm * 64 + x * 16 + l15) * 64 + kk + lq * 8];
#pragma unroll
      for (int x = 0; x < 4; ++x)
        bfr[x] = *(const bf16x8*)&Bs[(wn * 64 + x * 16 + l15) * 64 + kk + lq * 8];
#pragma unroll
      for (int mf = 0; mf < 4; ++mf)
#pragma unroll
        for (int nf = 0; nf < 4; ++nf)
          acc[mf][nf] = __builtin_amdgcn_mfma_f32_16x16x32_bf16(
              af[mf], bfr[nf], acc[mf][nf], 0, 0, 0);
    }
  }

  if (OUTM == 0) {
#pragma unroll
    for (int mf = 0; mf < 4; ++mf)
#pragma unroll
      for (int nf = 0; nf < 4; ++nf) {
        int col = n0 + wn * 64 + nf * 16 + l15;
        int row0 = m0 + wm * 64 + mf * 16 + lq * 4;
        if (col < 1024) {
#pragma unroll
          for (int i = 0; i < 4; ++i)
            Qb[(size_t)(row0 + i) * 1024 + col] = f2bf(acc[mf][nf][i]);
        } else if (col < 2048) {
#pragma unroll
          for (int i = 0; i < 4; ++i)
            Kb[(size_t)(row0 + i) * 1024 + col - 1024] = f2bf(acc[mf][nf][i]);
        } else {
          int np = col - 2048, h = np >> 6, d = np & 63;
          int b = row0 >> 11, s0 = row0 & 2047;
          uint2 w;
          w.x = pk2(acc[mf][nf][0], acc[mf][nf][1]);
          w.y = pk2(acc[mf][nf][2], acc[mf][nf][3]);
          *(uint2*)&VTg[((size_t)(b * 16 + h) * 64 + d) * 2048 + s0] = w;
        }
      }
  } else {
    bool f32out = (*mode == 0);
#pragma unroll
    for (int mf = 0; mf < 4; ++mf)
#pragma unroll
      for (int nf = 0; nf < 4; ++nf) {
        int col = n0 + wn * 64 + nf * 16 + l15;
#pragma unroll
        for (int i = 0; i < 4; ++i) {
          int row = m0 + wm * 64 + mf * 16 + lq * 4 + i;
          float v = acc[mf][nf][i];
          if (f32out) Cf[(size_t)row * N + col] = v;
          else        Qb[(size_t)row * N + col] = f2bf(v);
        }
      }
  }
}

// ---------------- flash attention (causal), HS=64, Q-tile 128, KV-tile 128 ---
// Grid: 1024 blocks, 1D. XCD-locality mapping: XCD x works (b,h) groups
// {x, 8+x, ..., 56+x} sequentially, heavy q-tiles first. 4 waves x 32 q-rows.
// exp2-domain online softmax; l via ones-column MFMA; conditional rescale.
__global__ __launch_bounds__(256) void attn_kernel(
    const u16* __restrict__ Qb, const u16* __restrict__ Kb,
    const u16* __restrict__ VT, u16* __restrict__ O) {
  constexpr int LDP = 136;
  constexpr float SC = 0.18033688f;  // 0.125 * log2(e)
  __shared__ __align__(16) u16 Ps[4][32 * LDP];
  int id = blockIdx.x;
  int xcd = id & 7, slot = id >> 3;
  int g = (slot >> 4) * 8 + xcd;          // (b,h) group, per-XCD sequential
  int qt = 15 - (slot & 15);              // heavy q-tiles dispatch first
  int h = g & 15, b = g >> 4;
  int tid = threadIdx.x, wid = tid >> 6, lane = tid & 63;
  int l15 = lane & 15, lq = lane >> 4;
  u16* ps = &Ps[wid][0];

  const size_t qoff = (size_t)b * 2048 * 1024 + h * 64;
  const u16* Qp = Qb + qoff;
  const u16* Kp = Kb + qoff;
  const u16* Vp = VT + ((size_t)(b * 16 + h) << 17);
  u16* Op = O + qoff;

  bf16x8 ones;
#pragma unroll
  for (int j = 0; j < 8; ++j) ones[j] = (__bf16)1.0f;

  int q0 = qt * 128;
  bf16x8 qf[2][2];
#pragma unroll
  for (int mf = 0; mf < 2; ++mf)
#pragma unroll
    for (int kf = 0; kf < 2; ++kf)
      qf[mf][kf] = *(const bf16x8*)(Qp + (size_t)(q0 + wid * 32 + mf * 16 + l15) * 1024 +
                                    kf * 32 + lq * 8);
  float m_i[2][4];
#pragma unroll
  for (int mf = 0; mf < 2; ++mf)
#pragma unroll
    for (int i = 0; i < 4; ++i) m_i[mf][i] = -1e30f;
  f32x4 o_acc[2][4] = {};
  f32x4 lacc[2] = {};

  for (int t = 0; t <= qt; ++t) {
    int k0 = t * 128;
    // ---- QK^T (raw scores) ----
    f32x4 s[2][8] = {};
#pragma unroll
    for (int kf = 0; kf < 2; ++kf)
#pragma unroll
      for (int nf = 0; nf < 8; ++nf) {
        bf16x8 kfr = *(const bf16x8*)(Kp + (size_t)(k0 + nf * 16 + l15) * 1024 +
                                      kf * 32 + lq * 8);
#pragma unroll
        for (int mf = 0; mf < 2; ++mf)
          s[mf][nf] = __builtin_amdgcn_mfma_f32_16x16x32_bf16(
              qf[mf][kf], kfr, s[mf][nf], 0, 0, 0);
      }
    // ---- causal mask on diagonal tile (raw -inf) ----
    if (t == qt) {
#pragma unroll
      for (int mf = 0; mf < 2; ++mf)
#pragma unroll
        for (int nf = 0; nf < 8; ++nf) {
          int gk = nf * 16 + l15;
#pragma unroll
          for (int i = 0; i < 4; ++i) {
            int gq = wid * 32 + mf * 16 + lq * 4 + i;
            if (gk > gq) s[mf][nf][i] = -1e30f;
          }
        }
    }
    // ---- row max (raw domain), 16-lane reduce ----
    float tmax[2][4];
#pragma unroll
    for (int mf = 0; mf < 2; ++mf)
#pragma unroll
      for (int i = 0; i < 4; ++i) {
        float m = s[mf][0][i];
#pragma unroll
        for (int nf = 1; nf < 8; ++nf) m = fmaxf(m, s[mf][nf][i]);
        tmax[mf][i] = m;
      }
#pragma unroll
    for (int msk = 1; msk <= 8; msk <<= 1)
#pragma unroll
      for (int mf = 0; mf < 2; ++mf)
#pragma unroll
        for (int i = 0; i < 4; ++i)
          tmax[mf][i] = fmaxf(tmax[mf][i], __shfl_xor(tmax[mf][i], msk, 64));
    // ---- new running max (exp2 domain); rescale only if it grew ----
    float mnew[2][4], d = 0.f;
#pragma unroll
    for (int mf = 0; mf < 2; ++mf)
#pragma unroll
      for (int i = 0; i < 4; ++i) {
        mnew[mf][i] = fmaxf(m_i[mf][i], tmax[mf][i] * SC);
        d = fmaxf(d, mnew[mf][i] - m_i[mf][i]);
      }
    if (__any(d > 0.f)) {
#pragma unroll
      for (int mf = 0; mf < 2; ++mf)
#pragma unroll
        for (int i = 0; i < 4; ++i) {
          float a = __builtin_amdgcn_exp2f(m_i[mf][i] - mnew[mf][i]);
          m_i[mf][i] = mnew[mf][i];
#pragma unroll
          for (int nf = 0; nf < 4; ++nf) o_acc[mf][nf][i] *= a;
          lacc[mf][i] *= a;
        }
    }
    // ---- P = exp2(s*SC - m), write bf16 to per-wave LDS slab ----
#pragma unroll
    for (int mf = 0; mf < 2; ++mf)
#pragma unroll
      for (int nf = 0; nf < 8; ++nf)
#pragma unroll
        for (int i = 0; i < 4; ++i) {
          float p = __builtin_amdgcn_exp2f(fmaf(s[mf][nf][i], SC, -m_i[mf][i]));
          ps[(mf * 16 + lq * 4 + i) * LDP + nf * 16 + l15] = f2bf(p);
        }
    // ---- PV + l (ones-column MFMA) ----
#pragma unroll
    for (int kf4 = 0; kf4 < 4; ++kf4) {
      bf16x8 pa0 = *(const bf16x8*)&ps[(l15) * LDP + kf4 * 32 + lq * 8];
      bf16x8 pa1 = *(const bf16x8*)&ps[(16 + l15) * LDP + kf4 * 32 + lq * 8];
      lacc[0] = __builtin_amdgcn_mfma_f32_16x16x32_bf16(pa0, ones, lacc[0], 0, 0, 0);
      lacc[1] = __builtin_amdgcn_mfma_f32_16x16x32_bf16(pa1, ones, lacc[1], 0, 0, 0);
#pragma unroll
      for (int nf = 0; nf < 4; ++nf) {
        bf16x8 vb = *(const bf16x8*)(Vp + (size_t)(nf * 16 + l15) * 2048 +
                                     k0 + kf4 * 32 + lq * 8);
        o_acc[0][nf] = __builtin_amdgcn_mfma_f32_16x16x32_bf16(pa0, vb, o_acc[0][nf], 0, 0, 0);
        o_acc[1][nf] = __builtin_amdgcn_mfma_f32_16x16x32_bf16(pa1, vb, o_acc[1][nf], 0, 0, 0);
      }
    }
  }  // kv tiles
  // ---- epilogue: O = o_acc / l (l identical across the 16 C-columns) ----
  float rinv[2][4];
#pragma unroll
  for (int mf = 0; mf < 2; ++mf)
#pragma unroll
    for (int i = 0; i < 4; ++i) rinv[mf][i] = 1.0f / lacc[mf][i];
#pragma unroll
  for (int mf = 0; mf < 2; ++mf)
#pragma unroll
    for (int nf = 0; nf < 4; ++nf)
#pragma unroll
      for (int i = 0; i < 4; ++i) {
        int row = q0 + wid * 32 + mf * 16 + lq * 4 + i;
        Op[(size_t)row * 1024 + nf * 16 + l15] = f2bf(o_acc[mf][nf][i] * rinv[mf][i]);
      }
}

// ---------------- launch ------------------------------------------------------
extern "C" void kernel_launch(void* const* d_in, const int* in_sizes, int n_in,
                              void* d_out, int out_size, void* d_ws, size_t ws_size,
                              hipStream_t stream) {
  (void)in_sizes; (void)n_in; (void)out_size; (void)ws_size;
  const void* x  = d_in[0];
  const void* Wq = d_in[1];
  const void* Wk = d_in[2];
  const void* Wv = d_in[3];
  const void* Wo = d_in[4];
  const int SL = 2048, ED = 1024;
  const int M = 4 * SL;  // 8192

  char* ws = (char*)d_ws;
  u16* x_bf  = (u16*)(ws + 0);           // 16 MB (dead after QKV GEMM)
  u16* wT    = (u16*)(ws + 16777216);    // [3072][1024] bf16, 6 MB
  u16* wo_T  = (u16*)(ws + 23068672);    // [1024][1024] bf16, 2 MB
  u16* Qb    = (u16*)(ws + 25165824);    // [8192][1024] bf16, 16 MB
  u16* Kb    = (u16*)(ws + 41943040);    // [8192][1024] bf16, 16 MB
  u16* VTg   = (u16*)(ws + 58720256);    // [64][64][2048] bf16, 16 MB
  u16* attnb = x_bf;                     // overlay
  int* mode  = (int*)(ws + 75497472);

  probe_kernel<<<1, 64, 0, stream>>>((const u16*)x, mode);

  cast_x<<<(M * ED / 8) / 256, 256, 0, stream>>>(x, x_bf, M * ED, mode);
  tcast<<<dim3(16, 16), 256, 0, stream>>>(Wq, wT + 0,           ED, ED, mode);
  tcast<<<dim3(16, 16), 256, 0, stream>>>(Wk, wT + 1024 * 1024, ED, ED, mode);
  tcast<<<dim3(16, 16), 256, 0, stream>>>(Wv, wT + 2048 * 1024, ED, ED, mode);
  tcast<<<dim3(16, 16), 256, 0, stream>>>(Wo, wo_T,             ED, ED, mode);

  // QKV = x @ W  -> Qb, Kb, VTg (V transposed in epilogue)
  gemm_m97<0><<<dim3(M / 128, (3 * ED) / 128), 256, 0, stream>>>(
      x_bf, wT, Qb, Kb, VTg, nullptr, M, 3 * ED, ED, mode);

  // flash attention -> attnb [8192,1024] bf16
  attn_kernel<<<dim3(1024), 256, 0, stream>>>(Qb, Kb, VTg, attnb);

  // out = attnb @ Wo
  gemm_m97<1><<<dim3(M / 128, ED / 128), 256, 0, stream>>>(
      attnb, wo_T, (u16*)d_out, nullptr, nullptr, (float*)d_out, M, ED, ED, mode);
}

// Round 8
// 468.571 us; speedup vs baseline: 1.0615x; 1.0615x over previous
//
#include <hip/hip_runtime.h>

typedef unsigned short u16;
typedef unsigned int u32;
typedef __bf16 bf16x8 __attribute__((ext_vector_type(8)));
typedef float f32x4 __attribute__((ext_vector_type(4)));

__device__ __forceinline__ u16 f2bf(float f) {
  union { float f; u32 u; } v; v.f = f;
  u32 r = v.u + 0x7FFFu + ((v.u >> 16) & 1u);
  return (u16)(r >> 16);
}
__device__ __forceinline__ u32 pk2(float a, float b) {
  return (u32)f2bf(a) | ((u32)f2bf(b) << 16);
}
__device__ __forceinline__ u16 bfbits(float f) {
  union { __bf16 h; u16 u; } cv; cv.h = (__bf16)f; return cv.u;
}

typedef __attribute__((address_space(1))) const void* gvp;
typedef __attribute__((address_space(3))) void* lvp;
__device__ __forceinline__ void gl16(const u16* g, u16* l) {
  __builtin_amdgcn_global_load_lds((gvp)g, (lvp)l, 16, 0, 0);
}

// ---------------- dtype probe: 0 = f32 buffers, 1 = bf16 buffers --------------
__global__ void probe_kernel(const u16* __restrict__ x, int* __restrict__ mode) {
  if (threadIdx.x == 0 && blockIdx.x == 0) {
    int cnt = 0;
    for (int i = 0; i < 512; ++i) {
      int e = (x[i] >> 7) & 0xFF;
      cnt += (e >= 110 && e <= 134) ? 1 : 0;
    }
    *mode = (cnt >= 410) ? 1 : 0;
  }
}

// ---------------- x -> bf16 (contiguous) -------------------------------------
__global__ __launch_bounds__(256) void cast_x(const void* __restrict__ src,
                                              u16* __restrict__ dst, int n,
                                              const int* __restrict__ mode) {
  int i = (blockIdx.x * 256 + threadIdx.x) * 8;
  if (i >= n) return;
  uint4 out;
  if (*mode == 0) {
    const float* s = (const float*)src + i;
    float4 v0 = *(const float4*)s, v1 = *(const float4*)(s + 4);
    out.x = pk2(v0.x, v0.y); out.y = pk2(v0.z, v0.w);
    out.z = pk2(v1.x, v1.y); out.w = pk2(v1.z, v1.w);
  } else {
    out = *(const uint4*)((const u16*)src + i);
  }
  *(uint4*)(dst + i) = out;
}

// ---------------- transpose-cast: dst[n][k] = (bf16)src[k][n] ----------------
__global__ __launch_bounds__(256) void tcast(const void* __restrict__ src,
                                             u16* __restrict__ dst, int srcld,
                                             int dstld, const int* __restrict__ mode) {
  __shared__ __align__(16) u16 T[64 * 72];
  int k0 = blockIdx.x * 64, n0 = blockIdx.y * 64;
  int tid = threadIdx.x;
  bool bf = (*mode != 0);
#pragma unroll
  for (int p = 0; p < 2; ++p) {
    int idx = (tid + p * 256) * 8;
    int r = idx >> 6, c = idx & 63;
    uint4 o;
    if (!bf) {
      const float* s = (const float*)src + (size_t)(k0 + r) * srcld + n0 + c;
      float4 v0 = *(const float4*)s, v1 = *(const float4*)(s + 4);
      o.x = pk2(v0.x, v0.y); o.y = pk2(v0.z, v0.w);
      o.z = pk2(v1.x, v1.y); o.w = pk2(v1.z, v1.w);
    } else {
      o = *(const uint4*)((const u16*)src + (size_t)(k0 + r) * srcld + n0 + c);
    }
    *(uint4*)&T[r * 72 + c] = o;
  }
  __syncthreads();
#pragma unroll
  for (int p = 0; p < 2; ++p) {
    int idx = (tid + p * 256) * 8;
    int n = idx >> 6, kk = idx & 63;
    u16 v[8];
#pragma unroll
    for (int j = 0; j < 8; ++j) v[j] = T[(kk + j) * 72 + n];
    *(uint4*)(dst + (size_t)(n0 + n) * dstld + k0 + kk) = *(uint4*)v;
  }
}

// ---------------- m97-style GEMM: C[M,N] = A[M,K] @ Bt[N,K]^T ----------------
template<int OUTM>
__global__ __launch_bounds__(256) void gemm_m97(
    const u16* __restrict__ A, const u16* __restrict__ Bt,
    u16* __restrict__ Qb, u16* __restrict__ Kb, u16* __restrict__ VTg,
    float* __restrict__ Cf, int M, int N, int K, const int* __restrict__ mode) {
  __shared__ __align__(16) u16 As[128 * 64];
  __shared__ __align__(16) u16 Bs[128 * 64];
  int tid = threadIdx.x, wid = tid >> 6, lane = tid & 63;
  int wm = wid >> 1, wn = wid & 1, l15 = lane & 15, lq = lane >> 4;
  int nwg = gridDim.x * gridDim.y;
  int id = blockIdx.y * gridDim.x + blockIdx.x;
  int swz = (id & 7) * (nwg >> 3) + (id >> 3);
  int m0 = (swz % gridDim.x) * 128, n0 = (swz / gridDim.x) * 128;
  int rs = lane >> 3, cs = (lane & 7) * 8;

  f32x4 acc[4][4] = {};

  for (int k0 = 0; k0 < K; k0 += 64) {
    __syncthreads();
#pragma unroll
    for (int p = 0; p < 4; ++p) {
      int r = wid * 32 + p * 8;
      gl16(A  + (size_t)(m0 + r + rs) * K + k0 + cs, &As[r * 64]);
      gl16(Bt + (size_t)(n0 + r + rs) * K + k0 + cs, &Bs[r * 64]);
    }
    __syncthreads();
#pragma unroll
    for (int kk = 0; kk < 64; kk += 32) {
      bf16x8 af[4], bfr[4];
#pragma unroll
      for (int x = 0; x < 4; ++x)
        af[x] = *(const bf16x8*)&As[(wm * 64 + x * 16 + l15) * 64 + kk + lq * 8];
#pragma unroll
      for (int x = 0; x < 4; ++x)
        bfr[x] = *(const bf16x8*)&Bs[(wn * 64 + x * 16 + l15) * 64 + kk + lq * 8];
#pragma unroll
      for (int mf = 0; mf < 4; ++mf)
#pragma unroll
        for (int nf = 0; nf < 4; ++nf)
          acc[mf][nf] = __builtin_amdgcn_mfma_f32_16x16x32_bf16(
              af[mf], bfr[nf], acc[mf][nf], 0, 0, 0);
    }
  }

  if (OUTM == 0) {
#pragma unroll
    for (int mf = 0; mf < 4; ++mf)
#pragma unroll
      for (int nf = 0; nf < 4; ++nf) {
        int col = n0 + wn * 64 + nf * 16 + l15;
        int row0 = m0 + wm * 64 + mf * 16 + lq * 4;
        if (col < 1024) {
#pragma unroll
          for (int i = 0; i < 4; ++i)
            Qb[(size_t)(row0 + i) * 1024 + col] = f2bf(acc[mf][nf][i]);
        } else if (col < 2048) {
#pragma unroll
          for (int i = 0; i < 4; ++i)
            Kb[(size_t)(row0 + i) * 1024 + col - 1024] = f2bf(acc[mf][nf][i]);
        } else {
          int np = col - 2048, h = np >> 6, d = np & 63;
          int b = row0 >> 11, s0 = row0 & 2047;
          uint2 w;
          w.x = pk2(acc[mf][nf][0], acc[mf][nf][1]);
          w.y = pk2(acc[mf][nf][2], acc[mf][nf][3]);
          *(uint2*)&VTg[((size_t)(b * 16 + h) * 64 + d) * 2048 + s0] = w;
        }
      }
  } else {
    bool f32out = (*mode == 0);
#pragma unroll
    for (int mf = 0; mf < 4; ++mf)
#pragma unroll
      for (int nf = 0; nf < 4; ++nf) {
        int col = n0 + wn * 64 + nf * 16 + l15;
#pragma unroll
        for (int i = 0; i < 4; ++i) {
          int row = m0 + wm * 64 + mf * 16 + lq * 4 + i;
          float v = acc[mf][nf][i];
          if (f32out) Cf[(size_t)row * N + col] = v;
          else        Qb[(size_t)row * N + col] = f2bf(v);
        }
      }
  }
}

// ---------------- flash attention (causal), HS=64 ----------------------------
// QBLK=64 (4 waves x 16 q-rows), KVBLK=128. 1024 blocks; block = q-tile pair
// (p, 31-p) -> constant 17 kv-units. Same-XCD (b,h) grouping for K/V L2 reuse.
__global__ __launch_bounds__(256, 4) void attn_kernel(
    const u16* __restrict__ Qb, const u16* __restrict__ Kb,
    const u16* __restrict__ VT, u16* __restrict__ O) {
  constexpr int LDP = 136;
  constexpr float SC = 0.18033688f;  // 0.125 * log2(e)
  __shared__ __align__(16) u16 Ps[4][16 * LDP];
  int id = blockIdx.x;
  int xcd = id & 7, slot = id >> 3;           // slot 0..127
  int g = (slot >> 4) * 8 + xcd;              // (b,h) group: 8 per XCD
  int p = slot & 15;                          // pair index 0..15
  int h = g & 15, b = g >> 4;
  int tid = threadIdx.x, wid = tid >> 6, lane = tid & 63;
  int l15 = lane & 15, lq = lane >> 4;
  u16* ps = &Ps[wid][0];

  const size_t qoff = (size_t)b * 2048 * 1024 + h * 64;
  const u16* Qp = Qb + qoff;
  const u16* Kp = Kb + qoff;
  const u16* Vp = VT + ((size_t)(b * 16 + h) << 17);
  u16* Op = O + qoff;

  bf16x8 ones;
#pragma unroll
  for (int j = 0; j < 8; ++j) ones[j] = (__bf16)1.0f;

  int qts[2] = {31 - p, p};
  for (int qi = 0; qi < 2; ++qi) {
    int qt = qts[qi];
    int q0 = qt * 64;
    int td = qt >> 1;                 // diagonal kv-unit
    int dshift = (qt & 1) * 64;       // column shift of the diagonal within unit td
    // Q fragments (A-operand): row = q0 + wid*16 + l15, k = kf*32 + lq*8
    bf16x8 qf[2];
#pragma unroll
    for (int kf = 0; kf < 2; ++kf)
      qf[kf] = *(const bf16x8*)(Qp + (size_t)(q0 + wid * 16 + l15) * 1024 +
                                kf * 32 + lq * 8);
    float m_i[4] = {-1e30f, -1e30f, -1e30f, -1e30f};
    f32x4 o_acc[4] = {};
    f32x4 lacc = {};

    for (int t = 0; t <= td; ++t) {
      int k0 = t * 128;
      // ---- QK^T ----
      f32x4 s[8] = {};
      __builtin_amdgcn_s_setprio(1);
#pragma unroll
      for (int kf = 0; kf < 2; ++kf)
#pragma unroll
        for (int nf = 0; nf < 8; ++nf) {
          bf16x8 kfr = *(const bf16x8*)(Kp + (size_t)(k0 + nf * 16 + l15) * 1024 +
                                        kf * 32 + lq * 8);
          s[nf] = __builtin_amdgcn_mfma_f32_16x16x32_bf16(qf[kf], kfr, s[nf], 0, 0, 0);
        }
      __builtin_amdgcn_s_setprio(0);
      // ---- causal mask on diagonal unit ----
      // gq(local) = wid*16 + lq*4 + i + dshift; gk(local) = nf*16 + l15
      if (t == td) {
        int r = wid * 16 + lq * 4 + dshift;
#pragma unroll
        for (int nf = 0; nf < 8; ++nf) {
          int gk = nf * 16 + l15;
#pragma unroll
          for (int i = 0; i < 4; ++i)
            if (gk > r + i) s[nf][i] = -1e30f;
        }
      }
      // ---- row max (16-lane reduce across l15 groups) ----
      float tmax[4];
#pragma unroll
      for (int i = 0; i < 4; ++i) {
        float m = s[0][i];
#pragma unroll
        for (int nf = 1; nf < 8; ++nf) m = fmaxf(m, s[nf][i]);
        tmax[i] = m;
      }
#pragma unroll
      for (int msk = 1; msk <= 8; msk <<= 1)
#pragma unroll
        for (int i = 0; i < 4; ++i)
          tmax[i] = fmaxf(tmax[i], __shfl_xor(tmax[i], msk, 64));
      // ---- running max (exp2 domain); rescale only if grew ----
      float mnew[4], d = 0.f;
#pragma unroll
      for (int i = 0; i < 4; ++i) {
        mnew[i] = fmaxf(m_i[i], tmax[i] * SC);
        d = fmaxf(d, mnew[i] - m_i[i]);
      }
      if (__any(d > 0.f)) {
#pragma unroll
        for (int i = 0; i < 4; ++i) {
          float a = __builtin_amdgcn_exp2f(m_i[i] - mnew[i]);
          m_i[i] = mnew[i];
#pragma unroll
          for (int nf = 0; nf < 4; ++nf) o_acc[nf][i] *= a;
          lacc[i] *= a;
        }
      }
      // ---- P = exp2(s*SC - m) -> bf16 LDS (per-wave slab) ----
#pragma unroll
      for (int nf = 0; nf < 8; ++nf)
#pragma unroll
        for (int i = 0; i < 4; ++i) {
          float pv = __builtin_amdgcn_exp2f(fmaf(s[nf][i], SC, -m_i[i]));
          ps[(lq * 4 + i) * LDP + nf * 16 + l15] = bfbits(pv);
        }
      // ---- PV + l (ones-column MFMA) ----
      __builtin_amdgcn_s_setprio(1);
#pragma unroll
      for (int kf4 = 0; kf4 < 4; ++kf4) {
        bf16x8 pa = *(const bf16x8*)&ps[l15 * LDP + kf4 * 32 + lq * 8];
        lacc = __builtin_amdgcn_mfma_f32_16x16x32_bf16(pa, ones, lacc, 0, 0, 0);
#pragma unroll
        for (int nf = 0; nf < 4; ++nf) {
          bf16x8 vb = *(const bf16x8*)(Vp + (size_t)(nf * 16 + l15) * 2048 +
                                       k0 + kf4 * 32 + lq * 8);
          o_acc[nf] = __builtin_amdgcn_mfma_f32_16x16x32_bf16(pa, vb, o_acc[nf], 0, 0, 0);
        }
      }
      __builtin_amdgcn_s_setprio(0);
    }  // kv units
    // ---- epilogue ----
    float rinv[4];
#pragma unroll
    for (int i = 0; i < 4; ++i) rinv[i] = 1.0f / lacc[i];
#pragma unroll
    for (int nf = 0; nf < 4; ++nf)
#pragma unroll
      for (int i = 0; i < 4; ++i) {
        int row = q0 + wid * 16 + lq * 4 + i;
        Op[(size_t)row * 1024 + nf * 16 + l15] = f2bf(o_acc[nf][i] * rinv[i]);
      }
  }  // q-tile pair
}

// ---------------- launch ------------------------------------------------------
extern "C" void kernel_launch(void* const* d_in, const int* in_sizes, int n_in,
                              void* d_out, int out_size, void* d_ws, size_t ws_size,
                              hipStream_t stream) {
  (void)in_sizes; (void)n_in; (void)out_size; (void)ws_size;
  const void* x  = d_in[0];
  const void* Wq = d_in[1];
  const void* Wk = d_in[2];
  const void* Wv = d_in[3];
  const void* Wo = d_in[4];
  const int SL = 2048, ED = 1024;
  const int M = 4 * SL;  // 8192

  char* ws = (char*)d_ws;
  u16* x_bf  = (u16*)(ws + 0);           // 16 MB (dead after QKV GEMM)
  u16* wT    = (u16*)(ws + 16777216);    // [3072][1024] bf16, 6 MB
  u16* wo_T  = (u16*)(ws + 23068672);    // [1024][1024] bf16, 2 MB
  u16* Qb    = (u16*)(ws + 25165824);    // [8192][1024] bf16, 16 MB
  u16* Kb    = (u16*)(ws + 41943040);    // [8192][1024] bf16, 16 MB
  u16* VTg   = (u16*)(ws + 58720256);    // [64][64][2048] bf16, 16 MB
  u16* attnb = x_bf;                     // overlay
  int* mode  = (int*)(ws + 75497472);

  probe_kernel<<<1, 64, 0, stream>>>((const u16*)x, mode);

  cast_x<<<(M * ED / 8) / 256, 256, 0, stream>>>(x, x_bf, M * ED, mode);
  tcast<<<dim3(16, 16), 256, 0, stream>>>(Wq, wT + 0,           ED, ED, mode);
  tcast<<<dim3(16, 16), 256, 0, stream>>>(Wk, wT + 1024 * 1024, ED, ED, mode);
  tcast<<<dim3(16, 16), 256, 0, stream>>>(Wv, wT + 2048 * 1024, ED, ED, mode);
  tcast<<<dim3(16, 16), 256, 0, stream>>>(Wo, wo_T,             ED, ED, mode);

  // QKV = x @ W  -> Qb, Kb, VTg (V transposed in epilogue)
  gemm_m97<0><<<dim3(M / 128, (3 * ED) / 128), 256, 0, stream>>>(
      x_bf, wT, Qb, Kb, VTg, nullptr, M, 3 * ED, ED, mode);

  // flash attention -> attnb [8192,1024] bf16
  attn_kernel<<<dim3(1024), 256, 0, stream>>>(Qb, Kb, VTg, attnb);

  // out = attnb @ Wo
  gemm_m97<1><<<dim3(M / 128, ED / 128), 256, 0, stream>>>(
      attnb, wo_T, (u16*)d_out, nullptr, nullptr, (float*)d_out, M, ED, ED, mode);
}